// Round 1
// baseline (1098.099 us; speedup 1.0000x reference)
//
#include <hip/hip_runtime.h>
#include <hip/hip_bf16.h>

// ---------------------------------------------------------------------------
// Transformer-XL block on MI355X.  See header comment block in each kernel.
// Shapes: B=2, S=1024, M=1024, F=2048, D=1024, H=16, dh=64.
// Outputs (flat in d_out): out[2*1024*1024] fp32, attn[2*16*1024*2048] fp32,
//                          loss[1] fp32.
// ---------------------------------------------------------------------------

typedef __attribute__((ext_vector_type(8))) short bf16x8;
typedef __attribute__((ext_vector_type(4))) float f32x4;

#define MFMA16(a, b, c) __builtin_amdgcn_mfma_f32_16x16x32_bf16((a), (b), (c), 0, 0, 0)

__device__ __forceinline__ unsigned short f2bf(float f) {
  union { __hip_bfloat16 h; unsigned short u; } cv;
  cv.h = __float2bfloat16(f);
  return cv.u;
}

__device__ __forceinline__ float gelu_f(float x) {
  return 0.5f * x * (1.f + erff(x * 0.70710678118654752f));
}

struct W9 { const float* p[9]; };

// ---------------------------------------------------------------------------
// k_init: LayerNorm(concat(mem, inputs)) -> xt bf16 (B,F,D);
//         inputs -> inb bf16; rel_enc -> reb bf16;
//         9 weights -> wT bf16 TRANSPOSED (N,K) each 1Mel, order:
//         [wq, wke, wv, wkr, wf, w1, w2, wg1, wg2]; zero amax[32].
// grid 15360 x 256
// ---------------------------------------------------------------------------
__global__ __launch_bounds__(256) void k_init(
    const float* __restrict__ inputs, const float* __restrict__ mem,
    const float* __restrict__ rel_enc, const float* __restrict__ g1n,
    const float* __restrict__ b1n, W9 wp,
    unsigned short* __restrict__ xt, unsigned short* __restrict__ inb,
    unsigned short* __restrict__ reb, unsigned short* __restrict__ wT,
    float* __restrict__ amax) {
  __shared__ float red[8];
  int bid = blockIdx.x, tid = threadIdx.x;
  if (bid == 0 && tid < 32) amax[tid] = 0.f;
  if (bid < 4096) {
    int b = bid >> 11, fi = bid & 2047;
    const float* src = (fi < 1024)
        ? (mem + ((size_t)(b * 1024 + fi)) * 1024)
        : (inputs + ((size_t)(b * 1024 + fi - 1024)) * 1024);
    float4 x = ((const float4*)src)[tid];
    float s = x.x + x.y + x.z + x.w;
    float ss = x.x * x.x + x.y * x.y + x.z * x.z + x.w * x.w;
#pragma unroll
    for (int m = 32; m > 0; m >>= 1) {
      s += __shfl_down(s, m, 64);
      ss += __shfl_down(ss, m, 64);
    }
    int w = tid >> 6;
    if ((tid & 63) == 0) { red[w] = s; red[4 + w] = ss; }
    __syncthreads();
    s = red[0] + red[1] + red[2] + red[3];
    ss = red[4] + red[5] + red[6] + red[7];
    float mu = s * (1.f / 1024.f);
    float inv = rsqrtf(ss * (1.f / 1024.f) - mu * mu + 1e-5f);
    float4 g = ((const float4*)g1n)[tid];
    float4 bb = ((const float4*)b1n)[tid];
    ushort4 o;
    o.x = f2bf((x.x - mu) * inv * g.x + bb.x);
    o.y = f2bf((x.y - mu) * inv * g.y + bb.y);
    o.z = f2bf((x.z - mu) * inv * g.z + bb.z);
    o.w = f2bf((x.w - mu) * inv * g.w + bb.w);
    ((ushort4*)(xt + (size_t)bid * 1024))[tid] = o;
    if (fi >= 1024) {
      ushort4 r4;
      r4.x = f2bf(x.x); r4.y = f2bf(x.y); r4.z = f2bf(x.z); r4.w = f2bf(x.w);
      ((ushort4*)(inb + ((size_t)(b * 1024 + fi - 1024)) * 1024))[tid] = r4;
    }
  } else if (bid < 6144) {
    int r = bid - 4096;
    float4 x = ((const float4*)(rel_enc + (size_t)r * 1024))[tid];
    ushort4 o;
    o.x = f2bf(x.x); o.y = f2bf(x.y); o.z = f2bf(x.z); o.w = f2bf(x.w);
    ((ushort4*)(reb + (size_t)r * 1024))[tid] = o;
  } else {
    int idx = bid - 6144;
    int m = idx >> 10, n = idx & 1023;
    const float* srcw = wp.p[m];
    int k = tid * 4;
    ushort4 o;
    o.x = f2bf(srcw[(size_t)(k + 0) * 1024 + n]);
    o.y = f2bf(srcw[(size_t)(k + 1) * 1024 + n]);
    o.z = f2bf(srcw[(size_t)(k + 2) * 1024 + n]);
    o.w = f2bf(srcw[(size_t)(k + 3) * 1024 + n]);
    ((ushort4*)(wT + ((size_t)m << 20) + (size_t)n * 1024))[tid] = o;
  }
}

// ---------------------------------------------------------------------------
// k_ln: LayerNorm rows of fp32 (2048 x 1024) -> bf16
// ---------------------------------------------------------------------------
__global__ __launch_bounds__(256) void k_ln(
    const float* __restrict__ xin, const float* __restrict__ g1n,
    const float* __restrict__ b1n, unsigned short* __restrict__ outb) {
  __shared__ float red[8];
  int bid = blockIdx.x, tid = threadIdx.x;
  const float* src = xin + (size_t)bid * 1024;
  float4 x = ((const float4*)src)[tid];
  float s = x.x + x.y + x.z + x.w;
  float ss = x.x * x.x + x.y * x.y + x.z * x.z + x.w * x.w;
#pragma unroll
  for (int m = 32; m > 0; m >>= 1) {
    s += __shfl_down(s, m, 64);
    ss += __shfl_down(ss, m, 64);
  }
  int w = tid >> 6;
  if ((tid & 63) == 0) { red[w] = s; red[4 + w] = ss; }
  __syncthreads();
  s = red[0] + red[1] + red[2] + red[3];
  ss = red[4] + red[5] + red[6] + red[7];
  float mu = s * (1.f / 1024.f);
  float inv = rsqrtf(ss * (1.f / 1024.f) - mu * mu + 1e-5f);
  float4 g = ((const float4*)g1n)[tid];
  float4 bb = ((const float4*)b1n)[tid];
  ushort4 o;
  o.x = f2bf((x.x - mu) * inv * g.x + bb.x);
  o.y = f2bf((x.y - mu) * inv * g.y + bb.y);
  o.z = f2bf((x.z - mu) * inv * g.z + bb.z);
  o.w = f2bf((x.w - mu) * inv * g.w + bb.w);
  ((ushort4*)(outb + (size_t)bid * 1024))[tid] = o;
}

// ---------------------------------------------------------------------------
// Generic bf16 MFMA GEMM: C[M,Nt] = A[M,1024] @ Wt[Nt,1024]^T  (NT form)
// block 256 = 4 waves, tile 128x128, BK=64, 16x16x32 bf16 MFMA.
// LDS layout: 16B unit u(r,g) = g*128 + (r&~7) + ((r^g)&7)  (XOR swizzle,
// conflict-free ds_read_b128 / ds_write_b128).
// A-row remap (for q GEMM slicing x_tilde[:, -S:]): ar = r + add + (r>>10)*mul
// ---------------------------------------------------------------------------
__device__ __forceinline__ int lds_u(int r, int g) {
  return g * 128 + (r & ~7) + ((r ^ g) & 7);
}

enum { EP_KV = 0, EP_QUV, EP_BF16, EP_GELU_F32, EP_GATE1,
       EP_GELU_B_BF16, EP_GELU_B_F32, EP_GATE2 };

template <int EP>
__global__ __launch_bounds__(256, 2) void k_gemm(
    const unsigned short* __restrict__ A, const unsigned short* __restrict__ Bw,
    int arow_add, int arow_mul,
    const float* __restrict__ bias, const float* __restrict__ auxA,
    const float* __restrict__ auxB, void* __restrict__ out0,
    void* __restrict__ out1) {
  __shared__ __align__(16) unsigned short As[8192];
  __shared__ __align__(16) unsigned short Bs[8192];
  int tid = threadIdx.x;
  int lane = tid & 63, wave = tid >> 6;
  int quad = lane >> 4, col = lane & 15;
  int wm = wave >> 1, wn = wave & 1;
  int bm = blockIdx.y, bn = blockIdx.x;
  f32x4 acc[4][4] = {};
  int str = tid >> 3, stg = tid & 7;
  const unsigned short* aptr[4];
  const unsigned short* bptr[4];
  int wu[4];
#pragma unroll
  for (int i = 0; i < 4; ++i) {
    int r = str + 32 * i;
    int gr = bm * 128 + r;
    int ar = gr + arow_add + (gr >> 10) * arow_mul;
    aptr[i] = A + (size_t)ar * 1024 + stg * 8;
    bptr[i] = Bw + (size_t)(bn * 128 + r) * 1024 + stg * 8;
    wu[i] = lds_u(r, stg);
  }
  for (int kt = 0; kt < 16; ++kt) {
    int k0 = kt * 64;
    uint4 av[4], bv[4];
#pragma unroll
    for (int i = 0; i < 4; ++i) {
      av[i] = *(const uint4*)(aptr[i] + k0);
      bv[i] = *(const uint4*)(bptr[i] + k0);
    }
#pragma unroll
    for (int i = 0; i < 4; ++i) {
      ((uint4*)As)[wu[i]] = av[i];
      ((uint4*)Bs)[wu[i]] = bv[i];
    }
    __syncthreads();
#pragma unroll
    for (int ks = 0; ks < 2; ++ks) {
      bf16x8 af[4], bfr[4];
#pragma unroll
      for (int mi = 0; mi < 4; ++mi)
        af[mi] = ((const bf16x8*)As)[lds_u(wm * 64 + mi * 16 + col, ks * 4 + quad)];
#pragma unroll
      for (int ni = 0; ni < 4; ++ni)
        bfr[ni] = ((const bf16x8*)Bs)[lds_u(wn * 64 + ni * 16 + col, ks * 4 + quad)];
#pragma unroll
      for (int mi = 0; mi < 4; ++mi)
#pragma unroll
        for (int ni = 0; ni < 4; ++ni)
          acc[mi][ni] = MFMA16(af[mi], bfr[ni], acc[mi][ni]);
    }
    __syncthreads();
  }
  // epilogue: C/D layout: row = quad*4+r, col = lane&15 within each 16x16 tile
#pragma unroll
  for (int mi = 0; mi < 4; ++mi)
#pragma unroll
    for (int ni = 0; ni < 4; ++ni)
#pragma unroll
      for (int r = 0; r < 4; ++r) {
        int grow = bm * 128 + wm * 64 + mi * 16 + quad * 4 + r;
        int gcol = bn * 128 + wn * 64 + ni * 16 + col;
        float v = acc[mi][ni][r];
        size_t idx = (size_t)grow * 1024 + gcol;
        if constexpr (EP == EP_KV) {
          if (gcol < 1024) {
            ((unsigned short*)out0)[(size_t)grow * 1024 + gcol] = f2bf(v);
          } else {
            int nn = gcol - 1024, hh = nn >> 6, dd = nn & 63;
            int bb2 = grow >> 11, ff = grow & 2047;
            ((unsigned short*)out1)[(((size_t)bb2 * 16 + hh) * 64 + dd) * 2048 + ff] = f2bf(v);
          }
        } else if constexpr (EP == EP_QUV) {
          ((unsigned short*)out0)[idx] = f2bf(v + auxA[gcol]);
          ((unsigned short*)out1)[idx] = f2bf(v + auxB[gcol]);
        } else if constexpr (EP == EP_BF16) {
          ((unsigned short*)out0)[idx] = f2bf(v);
        } else if constexpr (EP == EP_GELU_F32) {
          ((float*)out0)[idx] = gelu_f(v);
        } else if constexpr (EP == EP_GATE1) {
          float a = v + bias[gcol];
          float sg = 1.f / (1.f + __expf(-a));
          float g1 = auxA[idx] + sg * auxB[idx];
          ((float*)out0)[idx] = g1;
          ((unsigned short*)out1)[idx] = f2bf(g1);
        } else if constexpr (EP == EP_GELU_B_BF16) {
          ((unsigned short*)out0)[idx] = f2bf(gelu_f(v + bias[gcol]));
        } else if constexpr (EP == EP_GELU_B_F32) {
          ((float*)out0)[idx] = gelu_f(v + bias[gcol]);
        } else {  // EP_GATE2
          float a = v + bias[gcol];
          float sg = 1.f / (1.f + __expf(-a));
          ((float*)out0)[idx] = auxA[idx] + sg * auxB[idx];
        }
      }
}

// ---------------------------------------------------------------------------
// Fused rel-pos attention.  grid (32 = B*H, 16 = S/64), block 256 (4 waves,
// each wave owns 16 query rows).  Two passes, no max-subtraction (scores are
// bounded ~|s|<1):
//  pass1: scores (A_C via qu@k^T, B_D via sliding-window R=qv@Qr^T + shuffle
//         diagonal gather), p=exp(s), row-sum, P@V accumulate (P via LDS
//         round-trip to MFMA A-layout).
//  pass2: recompute scores, write attn = p/rowsum (exact 0 in masked region),
//         track per-(b,h) max -> atomicMax.
// ---------------------------------------------------------------------------
__global__ __launch_bounds__(256, 2) void k_att(
    const unsigned short* __restrict__ qu, const unsigned short* __restrict__ qv,
    const unsigned short* __restrict__ kk, const unsigned short* __restrict__ vT,
    const unsigned short* __restrict__ Qr,
    float* __restrict__ attn, unsigned short* __restrict__ ao,
    float* __restrict__ amax) {
  __shared__ __align__(16) unsigned short Pl[4][512];
  int tid = threadIdx.x, lane = tid & 63, wave = tid >> 6;
  int quad = lane >> 4, col = lane & 15;
  int bh = blockIdx.x, qt = blockIdx.y;
  int b = bh >> 4, h = bh & 15;
  int ri = qt * 64 + wave * 16;

  bf16x8 quf[2], qvf[2];
  {
    const unsigned short* p0 = qu + ((size_t)(b * 1024 + ri + col)) * 1024 + h * 64 + quad * 8;
    quf[0] = *(const bf16x8*)p0;
    quf[1] = *(const bf16x8*)(p0 + 32);
    const unsigned short* p1 = qv + ((size_t)(b * 1024 + ri + col)) * 1024 + h * 64 + quad * 8;
    qvf[0] = *(const bf16x8*)p1;
    qvf[1] = *(const bf16x8*)(p1 + 32);
  }

  const unsigned short* qrbase = Qr + h * 64 + quad * 8;
  auto r_tile = [&](int cbase) -> f32x4 {
    int cr = cbase + col;
    cr = cr < 0 ? 0 : (cr > 2047 ? 2047 : cr);
    const unsigned short* p = qrbase + (size_t)cr * 1024;
    bf16x8 b0 = *(const bf16x8*)p;
    bf16x8 b1 = *(const bf16x8*)(p + 32);
    f32x4 z = {0.f, 0.f, 0.f, 0.f};
    z = MFMA16(qvf[0], b0, z);
    z = MFMA16(qvf[1], b1, z);
    return z;
  };

  f32x4 o4[4] = {};
  f32x4 srow = {0.f, 0.f, 0.f, 0.f};

  int jmax = ri + 15 + 1024;       // largest possibly-unmasked j for this wave
  int nch = (jmax >> 5) + 1;       // 32-wide chunks
  int cw = 1008 - ri;              // R-window start for tile j0t=0
  f32x4 Rcur = r_tile(cw);

  const unsigned short* kbase = kk + ((size_t)(b * 2048)) * 1024 + h * 64 + quad * 8;
  const unsigned short* vbase = vT + ((size_t)((b * 16 + h) * 64)) * 2048;

  for (int ch = 0; ch < nch; ++ch) {
    int j0 = ch * 32;
#pragma unroll
    for (int t = 0; t < 2; ++t) {
      int j0t = j0 + t * 16;
      int f = j0t + col;
      f = f > 2047 ? 2047 : f;
      const unsigned short* kp = kbase + (size_t)f * 1024;
      bf16x8 kf0 = *(const bf16x8*)kp;
      bf16x8 kf1 = *(const bf16x8*)(kp + 32);
      f32x4 ac = {0.f, 0.f, 0.f, 0.f};
      ac = MFMA16(quf[0], kf0, ac);
      ac = MFMA16(quf[1], kf1, ac);
      f32x4 Rnx = r_tile(cw + 16);
#pragma unroll
      for (int r = 0; r < 4; ++r) {
        int w = 15 + col - quad * 4 - r;           // window idx in [0,30]
        int src = quad * 16 + (w & 15);
        float bd0 = __shfl(Rcur[r], src, 64);
        float bd1 = __shfl(Rnx[r], src, 64);
        float bd = (w < 16) ? bd0 : bd1;
        float sc = (ac[r] + bd) * 0.03125f;
        int masked = (j0t + col) > (ri + quad * 4 + r + 1024);
        float p = masked ? 0.f : __expf(sc);
        srow[r] += p;
        Pl[wave][(quad * 4 + r) * 32 + t * 16 + col] = f2bf(p);
      }
      Rcur = Rnx;
      cw += 16;
    }
    asm volatile("s_waitcnt lgkmcnt(0)" ::: "memory");
    bf16x8 pf = *(const bf16x8*)&Pl[wave][col * 32 + quad * 8];
    int fb = j0 + quad * 8;
    if (fb > 2040) fb = 2040;
#pragma unroll
    for (int ni = 0; ni < 4; ++ni) {
      const unsigned short* vp = vbase + (size_t)(ni * 16 + col) * 2048 + fb;
      bf16x8 vf = *(const bf16x8*)vp;
      o4[ni] = MFMA16(pf, vf, o4[ni]);
    }
  }
  // row sums across the 16 column-lanes of each quad
#pragma unroll
  for (int r = 0; r < 4; ++r) {
    float v = srow[r];
    v += __shfl_xor(v, 1, 64);
    v += __shfl_xor(v, 2, 64);
    v += __shfl_xor(v, 4, 64);
    v += __shfl_xor(v, 8, 64);
    srow[r] = v;
  }
  f32x4 rinv;
#pragma unroll
  for (int r = 0; r < 4; ++r) rinv[r] = 1.f / srow[r];
  // write ao (bf16, (B,S,D))
#pragma unroll
  for (int ni = 0; ni < 4; ++ni)
#pragma unroll
    for (int r = 0; r < 4; ++r) {
      size_t idx = ((size_t)(b * 1024 + ri + quad * 4 + r)) * 1024 + h * 64 + ni * 16 + col;
      ao[idx] = f2bf(o4[ni][r] * rinv[r]);
    }
  // ---- pass 2: write normalized attn everywhere (zeros in masked region) ----
  float pmax = 0.f;
  cw = 1008 - ri;
  Rcur = r_tile(cw);
  float* arow0 = attn + ((size_t)bh * 1024 + ri + quad * 4) * 2048 + col;
  for (int jt = 0; jt < 128; ++jt) {
    int j0t = jt * 16;
    if (j0t <= jmax) {
      int f = j0t + col;
      f = f > 2047 ? 2047 : f;
      const unsigned short* kp = kbase + (size_t)f * 1024;
      bf16x8 kf0 = *(const bf16x8*)kp;
      bf16x8 kf1 = *(const bf16x8*)(kp + 32);
      f32x4 ac = {0.f, 0.f, 0.f, 0.f};
      ac = MFMA16(quf[0], kf0, ac);
      ac = MFMA16(quf[1], kf1, ac);
      f32x4 Rnx = r_tile(cw + 16);
#pragma unroll
      for (int r = 0; r < 4; ++r) {
        int w = 15 + col - quad * 4 - r;
        int src = quad * 16 + (w & 15);
        float bd0 = __shfl(Rcur[r], src, 64);
        float bd1 = __shfl(Rnx[r], src, 64);
        float bd = (w < 16) ? bd0 : bd1;
        float sc = (ac[r] + bd) * 0.03125f;
        int masked = (j0t + col) > (ri + quad * 4 + r + 1024);
        float p = masked ? 0.f : __expf(sc) * rinv[r];
        arow0[(size_t)r * 2048 + j0t] = p;
        pmax = fmaxf(pmax, p);
      }
      Rcur = Rnx;
      cw += 16;
    } else {
#pragma unroll
      for (int r = 0; r < 4; ++r) arow0[(size_t)r * 2048 + j0t] = 0.f;
    }
  }
  pmax = fmaxf(pmax, __shfl_xor(pmax, 1, 64));
  pmax = fmaxf(pmax, __shfl_xor(pmax, 2, 64));
  pmax = fmaxf(pmax, __shfl_xor(pmax, 4, 64));
  pmax = fmaxf(pmax, __shfl_xor(pmax, 8, 64));
  pmax = fmaxf(pmax, __shfl_xor(pmax, 16, 64));
  pmax = fmaxf(pmax, __shfl_xor(pmax, 32, 64));
  if (lane == 0) atomicMax((int*)(amax + bh), __float_as_int(pmax));
}

// ---------------------------------------------------------------------------
__global__ void k_loss(const float* __restrict__ amax, float* __restrict__ out) {
  int l = threadIdx.x;
  float v = (l < 32) ? amax[l] : 0.f;
  v += __shfl_xor(v, 1, 64);
  v += __shfl_xor(v, 2, 64);
  v += __shfl_xor(v, 4, 64);
  v += __shfl_xor(v, 8, 64);
  v += __shfl_xor(v, 16, 64);
  v += __shfl_xor(v, 32, 64);
  if (l == 0) out[0] = v * (1.f / 32.f);
}

// ---------------------------------------------------------------------------
extern "C" void kernel_launch(void* const* d_in, const int* in_sizes, int n_in,
                              void* d_out, int out_size, void* d_ws, size_t ws_size,
                              hipStream_t stream) {
  (void)in_sizes; (void)n_in; (void)out_size; (void)ws_size;
  const float* inputs = (const float*)d_in[0];
  const float* mem    = (const float*)d_in[1];
  const float* rel    = (const float*)d_in[2];
  const float* ln1g   = (const float*)d_in[4];
  const float* ln1b   = (const float*)d_in[5];
  const float* wq     = (const float*)d_in[6];
  const float* wke    = (const float*)d_in[7];
  const float* wkr    = (const float*)d_in[8];
  const float* wv     = (const float*)d_in[9];
  const float* wf     = (const float*)d_in[10];
  const float* up     = (const float*)d_in[11];
  const float* vp     = (const float*)d_in[12];
  const float* ln2g   = (const float*)d_in[13];
  const float* ln2b   = (const float*)d_in[14];
  const float* w1     = (const float*)d_in[15];
  const float* b1     = (const float*)d_in[16];
  const float* w2     = (const float*)d_in[17];
  const float* b2     = (const float*)d_in[18];
  const float* wg1    = (const float*)d_in[19];
  const float* bg1    = (const float*)d_in[20];
  const float* wg2    = (const float*)d_in[21];
  const float* bg2    = (const float*)d_in[22];

  // workspace layout (~62 MB + 128 B)
  char* ws = (char*)d_ws;
  unsigned short* wT  = (unsigned short*)(ws);              // 18 MB (9 x 1Mel)
  unsigned short* xt  = (unsigned short*)(ws + 18874368);   // 8 MB
  unsigned short* inb = (unsigned short*)(ws + 27262976);   // 4 MB
  unsigned short* reb = (unsigned short*)(ws + 31457280);   // 4 MB
  unsigned short* kb  = (unsigned short*)(ws + 35651584);   // 8 MB
  unsigned short* vTb = (unsigned short*)(ws + 44040192);   // 8 MB
  unsigned short* qub = (unsigned short*)(ws + 52428800);   // 4 MB
  unsigned short* qvb = (unsigned short*)(ws + 56623104);   // 4 MB
  unsigned short* Qrb = (unsigned short*)(ws + 60817408);   // 4 MB
  float* amax         = (float*)(ws + 65011712);            // 128 B
  // aliases onto buffers dead after attention:
  float* rmha = (float*)xt;          // 8 MB fp32
  unsigned short* aob = reb;         // 4 MB bf16
  float* g1f = (float*)kb;           // 8 MB fp32
  float* h2f = (float*)vTb;          // 8 MB fp32
  unsigned short* g1b = qub;
  unsigned short* h0b = qvb;
  unsigned short* h1b = Qrb;

  float* outp  = (float*)d_out;
  float* attnp = outp + 2097152;
  float* lossp = outp + 69206016;

  W9 wp;
  wp.p[0] = wq;  wp.p[1] = wke; wp.p[2] = wv;  wp.p[3] = wkr; wp.p[4] = wf;
  wp.p[5] = w1;  wp.p[6] = w2;  wp.p[7] = wg1; wp.p[8] = wg2;

  k_init<<<15360, 256, 0, stream>>>(inputs, mem, rel, ln1g, ln1b, wp,
                                    xt, inb, reb, wT, amax);
  // k|v fused: (B*F,1024) @ [wke|wv]^T  (N=2048)
  k_gemm<EP_KV><<<dim3(16, 32), 256, 0, stream>>>(
      xt, wT + (1u << 20), 0, 0, nullptr, nullptr, nullptr, kb, vTb);
  // q -> qu = q+u_param, qv = q+v_param  (A rows = x_tilde[:, -S:])
  k_gemm<EP_QUV><<<dim3(8, 16), 256, 0, stream>>>(
      xt, wT, 1024, 1024, nullptr, up, vp, qub, qvb);
  // Qr = rel_enc @ wkr
  k_gemm<EP_BF16><<<dim3(8, 16), 256, 0, stream>>>(
      reb, wT + 3u * (1u << 20), 0, 0, nullptr, nullptr, nullptr, Qrb, nullptr);
  // fused attention (writes attn output + ao + per-head max)
  k_att<<<dim3(32, 16), 256, 0, stream>>>(qub, qvb, kb, vTb, Qrb, attnp, aob, amax);
  // rmha = gelu(ao @ wf)
  k_gemm<EP_GELU_F32><<<dim3(8, 16), 256, 0, stream>>>(
      aob, wT + 4u * (1u << 20), 0, 0, nullptr, nullptr, nullptr, rmha, nullptr);
  // g1 = inputs + sigmoid(inputs@wg1 + bg1) * rmha
  k_gemm<EP_GATE1><<<dim3(8, 16), 256, 0, stream>>>(
      inb, wT + 7u * (1u << 20), 0, 0, bg1, inputs, rmha, g1f, g1b);
  // h0 = LN2(g1)
  k_ln<<<2048, 256, 0, stream>>>(g1f, ln2g, ln2b, h0b);
  // h1 = gelu(h0@w1 + b1)
  k_gemm<EP_GELU_B_BF16><<<dim3(8, 16), 256, 0, stream>>>(
      h0b, wT + 5u * (1u << 20), 0, 0, b1, nullptr, nullptr, h1b, nullptr);
  // h2 = gelu(h1@w2 + b2)
  k_gemm<EP_GELU_B_F32><<<dim3(8, 16), 256, 0, stream>>>(
      h1b, wT + 6u * (1u << 20), 0, 0, b2, nullptr, nullptr, h2f, nullptr);
  // out = g1 + sigmoid(g1@wg2 + bg2) * h2
  k_gemm<EP_GATE2><<<dim3(8, 16), 256, 0, stream>>>(
      g1b, wT + 8u * (1u << 20), 0, 0, bg2, g1f, h2f, outp, nullptr);
  // loss = mean of 32 per-(b,h) maxes
  k_loss<<<1, 64, 0, stream>>>(amax, lossp);
}

// Round 2
// 798.748 us; speedup vs baseline: 1.3748x; 1.3748x over previous
//
#include <hip/hip_runtime.h>
#include <hip/hip_bf16.h>

// ---------------------------------------------------------------------------
// Transformer-XL block on MI355X.  Shapes: B=2, S=1024, M=1024, F=2048,
// D=1024, H=16, dh=64.  Outputs: out[2M] fp32, attn[2*16*1024*2048] fp32,
// loss[1] fp32.
// ---------------------------------------------------------------------------

typedef __attribute__((ext_vector_type(8))) short bf16x8;
typedef __attribute__((ext_vector_type(4))) float f32x4;

#define MFMA16(a, b, c) __builtin_amdgcn_mfma_f32_16x16x32_bf16((a), (b), (c), 0, 0, 0)

__device__ __forceinline__ unsigned short f2bf(float f) {
  union { __hip_bfloat16 h; unsigned short u; } cv;
  cv.h = __float2bfloat16(f);
  return cv.u;
}

__device__ __forceinline__ float gelu_f(float x) {
  return 0.5f * x * (1.f + erff(x * 0.70710678118654752f));
}

struct W9 { const float* p[9]; };

// ---------------------------------------------------------------------------
// k_init: blocks [0,4096): LayerNorm(concat(mem,inputs)) -> xt bf16, inputs
//   -> inb bf16;  [4096,6144): rel_enc -> reb bf16;  [6144,8448): 9 weights
//   -> wT bf16 transposed via coalesced 64x64 LDS-transpose tiles.
// ---------------------------------------------------------------------------
__global__ __launch_bounds__(256) void k_init(
    const float* __restrict__ inputs, const float* __restrict__ mem,
    const float* __restrict__ rel_enc, const float* __restrict__ g1n,
    const float* __restrict__ b1n, W9 wp,
    unsigned short* __restrict__ xt, unsigned short* __restrict__ inb,
    unsigned short* __restrict__ reb, unsigned short* __restrict__ wT,
    float* __restrict__ amax) {
  int bid = blockIdx.x, tid = threadIdx.x;
  if (bid == 0 && tid < 32) amax[tid] = 0.f;
  if (bid < 4096) {
    __shared__ float red[8];
    int b = bid >> 11, fi = bid & 2047;
    const float* src = (fi < 1024)
        ? (mem + ((size_t)(b * 1024 + fi)) * 1024)
        : (inputs + ((size_t)(b * 1024 + fi - 1024)) * 1024);
    float4 x = ((const float4*)src)[tid];
    float s = x.x + x.y + x.z + x.w;
    float ss = x.x * x.x + x.y * x.y + x.z * x.z + x.w * x.w;
#pragma unroll
    for (int m = 32; m > 0; m >>= 1) {
      s += __shfl_down(s, m, 64);
      ss += __shfl_down(ss, m, 64);
    }
    int w = tid >> 6;
    if ((tid & 63) == 0) { red[w] = s; red[4 + w] = ss; }
    __syncthreads();
    s = red[0] + red[1] + red[2] + red[3];
    ss = red[4] + red[5] + red[6] + red[7];
    float mu = s * (1.f / 1024.f);
    float inv = rsqrtf(ss * (1.f / 1024.f) - mu * mu + 1e-5f);
    float4 g = ((const float4*)g1n)[tid];
    float4 bb = ((const float4*)b1n)[tid];
    ushort4 o;
    o.x = f2bf((x.x - mu) * inv * g.x + bb.x);
    o.y = f2bf((x.y - mu) * inv * g.y + bb.y);
    o.z = f2bf((x.z - mu) * inv * g.z + bb.z);
    o.w = f2bf((x.w - mu) * inv * g.w + bb.w);
    ((ushort4*)(xt + (size_t)bid * 1024))[tid] = o;
    if (fi >= 1024) {
      ushort4 r4;
      r4.x = f2bf(x.x); r4.y = f2bf(x.y); r4.z = f2bf(x.z); r4.w = f2bf(x.w);
      ((ushort4*)(inb + ((size_t)(b * 1024 + fi - 1024)) * 1024))[tid] = r4;
    }
  } else if (bid < 6144) {
    int r = bid - 4096;
    float4 x = ((const float4*)(rel_enc + (size_t)r * 1024))[tid];
    ushort4 o;
    o.x = f2bf(x.x); o.y = f2bf(x.y); o.z = f2bf(x.z); o.w = f2bf(x.w);
    ((ushort4*)(reb + (size_t)r * 1024))[tid] = o;
  } else {
    __shared__ float tl[64][65];
    int idx = bid - 6144;
    int m = idx >> 8;
    int t = idx & 255;
    int k0 = (t >> 4) << 6, n0 = (t & 15) << 6;
    const float* srcw = wp.p[m];
    int kr = tid >> 4, nc = (tid & 15) << 2;
#pragma unroll
    for (int i = 0; i < 4; ++i) {
      int krow = i * 16 + kr;
      float4 v = *(const float4*)(srcw + (size_t)(k0 + krow) * 1024 + n0 + nc);
      tl[nc + 0][krow] = v.x;
      tl[nc + 1][krow] = v.y;
      tl[nc + 2][krow] = v.z;
      tl[nc + 3][krow] = v.w;
    }
    __syncthreads();
    int n = tid >> 2, kc0 = (tid & 3) << 4;
    unsigned short* dst = wT + ((size_t)m << 20) + (size_t)(n0 + n) * 1024 + k0 + kc0;
#pragma unroll
    for (int q = 0; q < 4; ++q) {
      ushort4 o;
      o.x = f2bf(tl[n][kc0 + q * 4 + 0]);
      o.y = f2bf(tl[n][kc0 + q * 4 + 1]);
      o.z = f2bf(tl[n][kc0 + q * 4 + 2]);
      o.w = f2bf(tl[n][kc0 + q * 4 + 3]);
      *(ushort4*)(dst + q * 4) = o;
    }
  }
}

// ---------------------------------------------------------------------------
// k_ln: LayerNorm rows of fp32 (2048 x 1024) -> bf16
// ---------------------------------------------------------------------------
__global__ __launch_bounds__(256) void k_ln(
    const float* __restrict__ xin, const float* __restrict__ g1n,
    const float* __restrict__ b1n, unsigned short* __restrict__ outb) {
  __shared__ float red[8];
  int bid = blockIdx.x, tid = threadIdx.x;
  const float* src = xin + (size_t)bid * 1024;
  float4 x = ((const float4*)src)[tid];
  float s = x.x + x.y + x.z + x.w;
  float ss = x.x * x.x + x.y * x.y + x.z * x.z + x.w * x.w;
#pragma unroll
  for (int m = 32; m > 0; m >>= 1) {
    s += __shfl_down(s, m, 64);
    ss += __shfl_down(ss, m, 64);
  }
  int w = tid >> 6;
  if ((tid & 63) == 0) { red[w] = s; red[4 + w] = ss; }
  __syncthreads();
  s = red[0] + red[1] + red[2] + red[3];
  ss = red[4] + red[5] + red[6] + red[7];
  float mu = s * (1.f / 1024.f);
  float inv = rsqrtf(ss * (1.f / 1024.f) - mu * mu + 1e-5f);
  float4 g = ((const float4*)g1n)[tid];
  float4 bb = ((const float4*)b1n)[tid];
  ushort4 o;
  o.x = f2bf((x.x - mu) * inv * g.x + bb.x);
  o.y = f2bf((x.y - mu) * inv * g.y + bb.y);
  o.z = f2bf((x.z - mu) * inv * g.z + bb.z);
  o.w = f2bf((x.w - mu) * inv * g.w + bb.w);
  ((ushort4*)(outb + (size_t)bid * 1024))[tid] = o;
}

// ---------------------------------------------------------------------------
// GEMM: C[M,Nt] = A[M,1024] @ Wt[Nt,1024]^T, tile TM x 128, BK=64, 4 waves
// splitting the 128-col dim (32 cols each).  TM=32: grid (Nt/128, M/32);
// TM=64: grid (Nt/128, M/64).  XOR-swizzled LDS.
// ---------------------------------------------------------------------------
__device__ __forceinline__ int lds_u128(int r, int g) {
  return g * 128 + (r & ~7) + ((r ^ g) & 7);
}
template <int TM>
__device__ __forceinline__ int lds_uT(int r, int g) {
  return g * TM + (r & ~7) + ((r ^ g) & 7);
}

enum { EP_KV = 0, EP_QUV, EP_BF16, EP_GELU_F32, EP_GATE1,
       EP_GELU_B_BF16, EP_GELU_B_F32, EP_GATE2 };

template <int EP, int TM>
__global__ __launch_bounds__(256, 2) void k_gemm(
    const unsigned short* __restrict__ A, const unsigned short* __restrict__ Bw,
    int arow_add, int arow_mul,
    const float* __restrict__ bias, const float* __restrict__ auxA,
    const float* __restrict__ auxB, void* __restrict__ out0,
    void* __restrict__ out1) {
  constexpr int MI = TM / 16;
  constexpr int AU = TM / 32;
  __shared__ __align__(16) unsigned short As[TM * 64];
  __shared__ __align__(16) unsigned short Bs[128 * 64];
  int tid = threadIdx.x;
  int lane = tid & 63, wave = tid >> 6;
  int quad = lane >> 4, col = lane & 15;
  int bm = blockIdx.y, bn = blockIdx.x;
  f32x4 acc[MI][2] = {};
  int str = tid >> 3, stg = tid & 7;
  const unsigned short* aptr[AU];
  int au[AU];
  const unsigned short* bptr[4];
  int bu[4];
#pragma unroll
  for (int i = 0; i < AU; ++i) {
    int r = str + 32 * i;
    int gr = bm * TM + r;
    int ar = gr + arow_add + (gr >> 10) * arow_mul;
    aptr[i] = A + (size_t)ar * 1024 + stg * 8;
    au[i] = lds_uT<TM>(r, stg);
  }
#pragma unroll
  for (int i = 0; i < 4; ++i) {
    int r = str + 32 * i;
    bptr[i] = Bw + (size_t)(bn * 128 + r) * 1024 + stg * 8;
    bu[i] = lds_u128(r, stg);
  }
  for (int kt = 0; kt < 16; ++kt) {
    int k0 = kt * 64;
    uint4 av[AU], bv[4];
#pragma unroll
    for (int i = 0; i < AU; ++i) av[i] = *(const uint4*)(aptr[i] + k0);
#pragma unroll
    for (int i = 0; i < 4; ++i) bv[i] = *(const uint4*)(bptr[i] + k0);
#pragma unroll
    for (int i = 0; i < AU; ++i) ((uint4*)As)[au[i]] = av[i];
#pragma unroll
    for (int i = 0; i < 4; ++i) ((uint4*)Bs)[bu[i]] = bv[i];
    __syncthreads();
#pragma unroll
    for (int ks = 0; ks < 2; ++ks) {
      bf16x8 af[MI], bfr[2];
#pragma unroll
      for (int mi = 0; mi < MI; ++mi)
        af[mi] = ((const bf16x8*)As)[lds_uT<TM>(mi * 16 + col, ks * 4 + quad)];
#pragma unroll
      for (int ni = 0; ni < 2; ++ni)
        bfr[ni] = ((const bf16x8*)Bs)[lds_u128(wave * 32 + ni * 16 + col, ks * 4 + quad)];
#pragma unroll
      for (int mi = 0; mi < MI; ++mi)
#pragma unroll
        for (int ni = 0; ni < 2; ++ni)
          acc[mi][ni] = MFMA16(af[mi], bfr[ni], acc[mi][ni]);
    }
    __syncthreads();
  }
#pragma unroll
  for (int mi = 0; mi < MI; ++mi)
#pragma unroll
    for (int ni = 0; ni < 2; ++ni)
#pragma unroll
      for (int r = 0; r < 4; ++r) {
        int grow = bm * TM + mi * 16 + quad * 4 + r;
        int gcol = bn * 128 + wave * 32 + ni * 16 + col;
        float v = acc[mi][ni][r];
        size_t idx = (size_t)grow * 1024 + gcol;
        if constexpr (EP == EP_KV) {
          if (gcol < 1024) {
            ((unsigned short*)out0)[(size_t)grow * 1024 + gcol] = f2bf(v);
          } else {
            int nn = gcol - 1024, hh = nn >> 6, dd = nn & 63;
            int bb2 = grow >> 11, ff = grow & 2047;
            ((unsigned short*)out1)[(((size_t)bb2 * 16 + hh) * 64 + dd) * 2048 + ff] = f2bf(v);
          }
        } else if constexpr (EP == EP_QUV) {
          ((unsigned short*)out0)[idx] = f2bf(v + auxA[gcol]);
          ((unsigned short*)out1)[idx] = f2bf(v + auxB[gcol]);
        } else if constexpr (EP == EP_BF16) {
          ((unsigned short*)out0)[idx] = f2bf(v);
        } else if constexpr (EP == EP_GELU_F32) {
          ((float*)out0)[idx] = gelu_f(v);
        } else if constexpr (EP == EP_GATE1) {
          float a = v + bias[gcol];
          float sg = 1.f / (1.f + __expf(-a));
          float g1 = auxA[idx] + sg * auxB[idx];
          ((float*)out0)[idx] = g1;
          ((unsigned short*)out1)[idx] = f2bf(g1);
        } else if constexpr (EP == EP_GELU_B_BF16) {
          ((unsigned short*)out0)[idx] = f2bf(gelu_f(v + bias[gcol]));
        } else if constexpr (EP == EP_GELU_B_F32) {
          ((float*)out0)[idx] = gelu_f(v + bias[gcol]);
        } else {  // EP_GATE2
          float a = v + bias[gcol];
          float sg = 1.f / (1.f + __expf(-a));
          ((float*)out0)[idx] = auxA[idx] + sg * auxB[idx];
        }
      }
}

// ---------------------------------------------------------------------------
// Fused rel-pos attention, v2 (column-striped waves for occupancy).
// grid (32 = B*H, 64 = S/16); block 256 = 4 waves.  Block owns 16 query
// rows; wave w owns column stripe [w*512, w*512+512).
//  pass1: per-stripe scores (A_C + shifted B_D) -> p=exp(s), stripe rowsum,
//         stripe P@V; cross-wave LDS tree reduce of o and rowsum; write ao.
//  pass2: per-stripe recompute, write attn = p * rinv (0 in masked region),
//         per-(b,h) max -> atomicMax.
// ---------------------------------------------------------------------------
__global__ __launch_bounds__(256, 2) void k_att(
    const unsigned short* __restrict__ qu, const unsigned short* __restrict__ qv,
    const unsigned short* __restrict__ kk, const unsigned short* __restrict__ vT,
    const unsigned short* __restrict__ Qr,
    float* __restrict__ attn, unsigned short* __restrict__ ao,
    float* __restrict__ amax) {
  __shared__ __align__(16) unsigned short Pl[4][512];
  __shared__ __align__(16) float Ol[2][1024];
  __shared__ float Sl[4][16];
  __shared__ float Rinv[16];
  int tid = threadIdx.x, lane = tid & 63, wave = tid >> 6;
  int quad = lane >> 4, col = lane & 15;
  int bh = blockIdx.x, rt = blockIdx.y;
  int b = bh >> 4, h = bh & 15;
  int ri = rt * 16;

  bf16x8 quf[2], qvf[2];
  {
    const unsigned short* p0 = qu + ((size_t)(b * 1024 + ri + col)) * 1024 + h * 64 + quad * 8;
    quf[0] = *(const bf16x8*)p0;
    quf[1] = *(const bf16x8*)(p0 + 32);
    const unsigned short* p1 = qv + ((size_t)(b * 1024 + ri + col)) * 1024 + h * 64 + quad * 8;
    qvf[0] = *(const bf16x8*)p1;
    qvf[1] = *(const bf16x8*)(p1 + 32);
  }

  const unsigned short* qrbase = Qr + h * 64 + quad * 8;
  auto r_tile = [&](int cbase) -> f32x4 {
    int cr = cbase + col;
    cr = cr < 0 ? 0 : (cr > 2047 ? 2047 : cr);
    const unsigned short* p = qrbase + (size_t)cr * 1024;
    bf16x8 b0 = *(const bf16x8*)p;
    bf16x8 b1 = *(const bf16x8*)(p + 32);
    f32x4 z = {0.f, 0.f, 0.f, 0.f};
    z = MFMA16(qvf[0], b0, z);
    z = MFMA16(qvf[1], b1, z);
    return z;
  };

  const unsigned short* kbase = kk + ((size_t)(b * 2048)) * 1024 + h * 64 + quad * 8;
  const unsigned short* vbase = vT + ((size_t)((b * 16 + h) * 64)) * 2048;

  f32x4 o4[4] = {};
  f32x4 srow = {0.f, 0.f, 0.f, 0.f};
  int jmax = ri + 15 + 1024;
  int jlo = wave * 512;

  if (jlo <= jmax) {
    int hi = jmax < jlo + 511 ? jmax : jlo + 511;
    int nch = ((hi - jlo) >> 5) + 1;
    int cw = 1008 - ri + jlo;
    f32x4 Rcur = r_tile(cw);
    for (int ch = 0; ch < nch; ++ch) {
      int j0 = jlo + ch * 32;
#pragma unroll
      for (int t = 0; t < 2; ++t) {
        int j0t = j0 + t * 16;
        int f = j0t + col;
        f = f > 2047 ? 2047 : f;
        const unsigned short* kp = kbase + (size_t)f * 1024;
        bf16x8 kf0 = *(const bf16x8*)kp;
        bf16x8 kf1 = *(const bf16x8*)(kp + 32);
        f32x4 ac = {0.f, 0.f, 0.f, 0.f};
        ac = MFMA16(quf[0], kf0, ac);
        ac = MFMA16(quf[1], kf1, ac);
        f32x4 Rnx = r_tile(cw + 16);
#pragma unroll
        for (int r = 0; r < 4; ++r) {
          int w = 15 + col - quad * 4 - r;
          int src = quad * 16 + (w & 15);
          float bd0 = __shfl(Rcur[r], src, 64);
          float bd1 = __shfl(Rnx[r], src, 64);
          float bd = (w < 16) ? bd0 : bd1;
          float sc = (ac[r] + bd) * 0.03125f;
          int masked = (j0t + col) > (ri + quad * 4 + r + 1024);
          float p = masked ? 0.f : __expf(sc);
          srow[r] += p;
          Pl[wave][(quad * 4 + r) * 32 + t * 16 + col] = f2bf(p);
        }
        Rcur = Rnx;
        cw += 16;
      }
      asm volatile("s_waitcnt lgkmcnt(0)" ::: "memory");
      bf16x8 pf = *(const bf16x8*)&Pl[wave][col * 32 + quad * 8];
      int fb = j0 + quad * 8;
#pragma unroll
      for (int ni = 0; ni < 4; ++ni) {
        const unsigned short* vp = vbase + (size_t)(ni * 16 + col) * 2048 + fb;
        bf16x8 vf = *(const bf16x8*)vp;
        o4[ni] = MFMA16(pf, vf, o4[ni]);
      }
    }
  }
  // stripe row-sums (reduce across 16 col lanes of each quad)
#pragma unroll
  for (int r = 0; r < 4; ++r) {
    float v = srow[r];
    v += __shfl_xor(v, 1, 64);
    v += __shfl_xor(v, 2, 64);
    v += __shfl_xor(v, 4, 64);
    v += __shfl_xor(v, 8, 64);
    srow[r] = v;
  }
  if (col == 0) {
#pragma unroll
    for (int r = 0; r < 4; ++r) Sl[wave][quad * 4 + r] = srow[r];
  }
  if (wave >= 2) {
#pragma unroll
    for (int ni = 0; ni < 4; ++ni)
#pragma unroll
      for (int r = 0; r < 4; ++r)
        Ol[wave - 2][(quad * 4 + r) * 64 + ni * 16 + col] = o4[ni][r];
  }
  __syncthreads();
  if (tid < 16)
    Rinv[tid] = 1.f / (Sl[0][tid] + Sl[1][tid] + Sl[2][tid] + Sl[3][tid]);
  if (wave < 2) {
#pragma unroll
    for (int ni = 0; ni < 4; ++ni)
#pragma unroll
      for (int r = 0; r < 4; ++r) {
        int ix = (quad * 4 + r) * 64 + ni * 16 + col;
        o4[ni][r] += Ol[wave][ix];
        if (wave == 1) Ol[1][ix] = o4[ni][r];
      }
  }
  __syncthreads();
  if (wave == 0) {
#pragma unroll
    for (int ni = 0; ni < 4; ++ni)
#pragma unroll
      for (int r = 0; r < 4; ++r) {
        int ix = (quad * 4 + r) * 64 + ni * 16 + col;
        o4[ni][r] += Ol[1][ix];
        Ol[0][ix] = o4[ni][r];
      }
  }
  __syncthreads();
  {
    int row = tid >> 4, d0 = (tid & 15) << 2;
    float4 ov = *(const float4*)&Ol[0][row * 64 + d0];
    float rv = Rinv[row];
    ushort4 o;
    o.x = f2bf(ov.x * rv); o.y = f2bf(ov.y * rv);
    o.z = f2bf(ov.z * rv); o.w = f2bf(ov.w * rv);
    *(ushort4*)(ao + ((size_t)(b * 1024 + ri + row)) * 1024 + h * 64 + d0) = o;
  }
  // ---- pass 2: write normalized attn for this wave's stripe ----
  float rl[4];
#pragma unroll
  for (int r = 0; r < 4; ++r) rl[r] = Rinv[quad * 4 + r];
  float pmax = 0.f;
  int cw = 1008 - ri + jlo;
  f32x4 Rcur = r_tile(cw);
  float* arow0 = attn + ((size_t)bh * 1024 + ri + quad * 4) * 2048 + col;
  for (int jt = 0; jt < 32; ++jt) {
    int j0t = jlo + jt * 16;
    if (j0t <= jmax) {
      int f = j0t + col;
      f = f > 2047 ? 2047 : f;
      const unsigned short* kp = kbase + (size_t)f * 1024;
      bf16x8 kf0 = *(const bf16x8*)kp;
      bf16x8 kf1 = *(const bf16x8*)(kp + 32);
      f32x4 ac = {0.f, 0.f, 0.f, 0.f};
      ac = MFMA16(quf[0], kf0, ac);
      ac = MFMA16(quf[1], kf1, ac);
      f32x4 Rnx = r_tile(cw + 16);
#pragma unroll
      for (int r = 0; r < 4; ++r) {
        int w = 15 + col - quad * 4 - r;
        int src = quad * 16 + (w & 15);
        float bd0 = __shfl(Rcur[r], src, 64);
        float bd1 = __shfl(Rnx[r], src, 64);
        float bd = (w < 16) ? bd0 : bd1;
        float sc = (ac[r] + bd) * 0.03125f;
        int masked = (j0t + col) > (ri + quad * 4 + r + 1024);
        float p = masked ? 0.f : __expf(sc) * rl[r];
        arow0[(size_t)r * 2048 + j0t] = p;
        pmax = fmaxf(pmax, p);
      }
      Rcur = Rnx;
      cw += 16;
    } else {
#pragma unroll
      for (int r = 0; r < 4; ++r) arow0[(size_t)r * 2048 + j0t] = 0.f;
    }
  }
  pmax = fmaxf(pmax, __shfl_xor(pmax, 1, 64));
  pmax = fmaxf(pmax, __shfl_xor(pmax, 2, 64));
  pmax = fmaxf(pmax, __shfl_xor(pmax, 4, 64));
  pmax = fmaxf(pmax, __shfl_xor(pmax, 8, 64));
  pmax = fmaxf(pmax, __shfl_xor(pmax, 16, 64));
  pmax = fmaxf(pmax, __shfl_xor(pmax, 32, 64));
  if (lane == 0) atomicMax((int*)(amax + bh), __float_as_int(pmax));
}

// ---------------------------------------------------------------------------
__global__ void k_loss(const float* __restrict__ amax, float* __restrict__ out) {
  int l = threadIdx.x;
  float v = (l < 32) ? amax[l] : 0.f;
  v += __shfl_xor(v, 1, 64);
  v += __shfl_xor(v, 2, 64);
  v += __shfl_xor(v, 4, 64);
  v += __shfl_xor(v, 8, 64);
  v += __shfl_xor(v, 16, 64);
  v += __shfl_xor(v, 32, 64);
  if (l == 0) out[0] = v * (1.f / 32.f);
}

// ---------------------------------------------------------------------------
extern "C" void kernel_launch(void* const* d_in, const int* in_sizes, int n_in,
                              void* d_out, int out_size, void* d_ws, size_t ws_size,
                              hipStream_t stream) {
  (void)in_sizes; (void)n_in; (void)out_size; (void)ws_size;
  const float* inputs = (const float*)d_in[0];
  const float* mem    = (const float*)d_in[1];
  const float* rel    = (const float*)d_in[2];
  const float* ln1g   = (const float*)d_in[4];
  const float* ln1b   = (const float*)d_in[5];
  const float* wq     = (const float*)d_in[6];
  const float* wke    = (const float*)d_in[7];
  const float* wkr    = (const float*)d_in[8];
  const float* wv     = (const float*)d_in[9];
  const float* wf     = (const float*)d_in[10];
  const float* up     = (const float*)d_in[11];
  const float* vp     = (const float*)d_in[12];
  const float* ln2g   = (const float*)d_in[13];
  const float* ln2b   = (const float*)d_in[14];
  const float* w1     = (const float*)d_in[15];
  const float* b1     = (const float*)d_in[16];
  const float* w2     = (const float*)d_in[17];
  const float* b2     = (const float*)d_in[18];
  const float* wg1    = (const float*)d_in[19];
  const float* bg1    = (const float*)d_in[20];
  const float* wg2    = (const float*)d_in[21];
  const float* bg2    = (const float*)d_in[22];

  char* ws = (char*)d_ws;
  unsigned short* wT  = (unsigned short*)(ws);              // 18 MB (9 x 1Mel)
  unsigned short* xt  = (unsigned short*)(ws + 18874368);   // 8 MB
  unsigned short* inb = (unsigned short*)(ws + 27262976);   // 4 MB
  unsigned short* reb = (unsigned short*)(ws + 31457280);   // 4 MB
  unsigned short* kb  = (unsigned short*)(ws + 35651584);   // 8 MB
  unsigned short* vTb = (unsigned short*)(ws + 44040192);   // 8 MB
  unsigned short* qub = (unsigned short*)(ws + 52428800);   // 4 MB
  unsigned short* qvb = (unsigned short*)(ws + 56623104);   // 4 MB
  unsigned short* Qrb = (unsigned short*)(ws + 60817408);   // 4 MB
  float* amax         = (float*)(ws + 65011712);            // 128 B
  float* rmha = (float*)xt;          // aliases onto dead buffers
  unsigned short* aob = reb;
  float* g1f = (float*)kb;
  float* h2f = (float*)vTb;
  unsigned short* g1b = qub;
  unsigned short* h0b = qvb;
  unsigned short* h1b = Qrb;

  float* outp  = (float*)d_out;
  float* attnp = outp + 2097152;
  float* lossp = outp + 69206016;

  W9 wp;
  wp.p[0] = wq;  wp.p[1] = wke; wp.p[2] = wv;  wp.p[3] = wkr; wp.p[4] = wf;
  wp.p[5] = w1;  wp.p[6] = w2;  wp.p[7] = wg1; wp.p[8] = wg2;

  k_init<<<8448, 256, 0, stream>>>(inputs, mem, rel, ln1g, ln1b, wp,
                                   xt, inb, reb, wT, amax);
  // k|v fused: (B*F,1024) @ [wke|wv]^T  (N=2048)
  k_gemm<EP_KV, 64><<<dim3(16, 64), 256, 0, stream>>>(
      xt, wT + (1u << 20), 0, 0, nullptr, nullptr, nullptr, kb, vTb);
  // q -> qu = q+u_param, qv = q+v_param  (A rows = x_tilde[:, -S:])
  k_gemm<EP_QUV, 32><<<dim3(8, 64), 256, 0, stream>>>(
      xt, wT, 1024, 1024, nullptr, up, vp, qub, qvb);
  // Qr = rel_enc @ wkr
  k_gemm<EP_BF16, 32><<<dim3(8, 64), 256, 0, stream>>>(
      reb, wT + 3u * (1u << 20), 0, 0, nullptr, nullptr, nullptr, Qrb, nullptr);
  // fused attention
  k_att<<<dim3(32, 64), 256, 0, stream>>>(qub, qvb, kb, vTb, Qrb, attnp, aob, amax);
  // rmha = gelu(ao @ wf)
  k_gemm<EP_GELU_F32, 32><<<dim3(8, 64), 256, 0, stream>>>(
      aob, wT + 4u * (1u << 20), 0, 0, nullptr, nullptr, nullptr, rmha, nullptr);
  // g1 = inputs + sigmoid(inputs@wg1 + bg1) * rmha
  k_gemm<EP_GATE1, 32><<<dim3(8, 64), 256, 0, stream>>>(
      inb, wT + 7u * (1u << 20), 0, 0, bg1, inputs, rmha, g1f, g1b);
  // h0 = LN2(g1)
  k_ln<<<2048, 256, 0, stream>>>(g1f, ln2g, ln2b, h0b);
  // h1 = gelu(h0@w1 + b1)
  k_gemm<EP_GELU_B_BF16, 32><<<dim3(8, 64), 256, 0, stream>>>(
      h0b, wT + 5u * (1u << 20), 0, 0, b1, nullptr, nullptr, h1b, nullptr);
  // h2 = gelu(h1@w2 + b2)
  k_gemm<EP_GELU_B_F32, 32><<<dim3(8, 64), 256, 0, stream>>>(
      h1b, wT + 6u * (1u << 20), 0, 0, b2, nullptr, nullptr, h2f, nullptr);
  // out = g1 + sigmoid(g1@wg2 + bg2) * h2
  k_gemm<EP_GATE2, 32><<<dim3(8, 64), 256, 0, stream>>>(
      g1b, wT + 8u * (1u << 20), 0, 0, bg2, g1f, h2f, outp, nullptr);
  k_loss<<<1, 64, 0, stream>>>(amax, lossp);
}

// Round 3
// 786.632 us; speedup vs baseline: 1.3959x; 1.0154x over previous
//
#include <hip/hip_runtime.h>
#include <hip/hip_bf16.h>

// ---------------------------------------------------------------------------
// Transformer-XL block on MI355X.  Shapes: B=2, S=1024, M=1024, F=2048,
// D=1024, H=16, dh=64.  Outputs: out[2M] fp32, attn[2*16*1024*2048] fp32,
// loss[1] fp32.
// ---------------------------------------------------------------------------

typedef __attribute__((ext_vector_type(8))) short bf16x8;
typedef __attribute__((ext_vector_type(4))) float f32x4;

#define MFMA16(a, b, c) __builtin_amdgcn_mfma_f32_16x16x32_bf16((a), (b), (c), 0, 0, 0)

__device__ __forceinline__ unsigned short f2bf(float f) {
  union { __hip_bfloat16 h; unsigned short u; } cv;
  cv.h = __float2bfloat16(f);
  return cv.u;
}

__device__ __forceinline__ float gelu_f(float x) {
  return 0.5f * x * (1.f + erff(x * 0.70710678118654752f));
}

struct W9 { const float* p[9]; };

// ---------------------------------------------------------------------------
// k_init: [0,4096): LN(concat(mem,inputs))->xt bf16, inputs->inb bf16;
// [4096,6144): rel_enc->reb; [6144,8448): weights -> wT bf16 transposed.
// ---------------------------------------------------------------------------
__global__ __launch_bounds__(256) void k_init(
    const float* __restrict__ inputs, const float* __restrict__ mem,
    const float* __restrict__ rel_enc, const float* __restrict__ g1n,
    const float* __restrict__ b1n, W9 wp,
    unsigned short* __restrict__ xt, unsigned short* __restrict__ inb,
    unsigned short* __restrict__ reb, unsigned short* __restrict__ wT,
    float* __restrict__ amax) {
  int bid = blockIdx.x, tid = threadIdx.x;
  if (bid == 0 && tid < 32) amax[tid] = 0.f;
  if (bid < 4096) {
    __shared__ float red[8];
    int b = bid >> 11, fi = bid & 2047;
    const float* src = (fi < 1024)
        ? (mem + ((size_t)(b * 1024 + fi)) * 1024)
        : (inputs + ((size_t)(b * 1024 + fi - 1024)) * 1024);
    float4 x = ((const float4*)src)[tid];
    float s = x.x + x.y + x.z + x.w;
    float ss = x.x * x.x + x.y * x.y + x.z * x.z + x.w * x.w;
#pragma unroll
    for (int m = 32; m > 0; m >>= 1) {
      s += __shfl_down(s, m, 64);
      ss += __shfl_down(ss, m, 64);
    }
    int w = tid >> 6;
    if ((tid & 63) == 0) { red[w] = s; red[4 + w] = ss; }
    __syncthreads();
    s = red[0] + red[1] + red[2] + red[3];
    ss = red[4] + red[5] + red[6] + red[7];
    float mu = s * (1.f / 1024.f);
    float inv = rsqrtf(ss * (1.f / 1024.f) - mu * mu + 1e-5f);
    float4 g = ((const float4*)g1n)[tid];
    float4 bb = ((const float4*)b1n)[tid];
    ushort4 o;
    o.x = f2bf((x.x - mu) * inv * g.x + bb.x);
    o.y = f2bf((x.y - mu) * inv * g.y + bb.y);
    o.z = f2bf((x.z - mu) * inv * g.z + bb.z);
    o.w = f2bf((x.w - mu) * inv * g.w + bb.w);
    ((ushort4*)(xt + (size_t)bid * 1024))[tid] = o;
    if (fi >= 1024) {
      ushort4 r4;
      r4.x = f2bf(x.x); r4.y = f2bf(x.y); r4.z = f2bf(x.z); r4.w = f2bf(x.w);
      ((ushort4*)(inb + ((size_t)(b * 1024 + fi - 1024)) * 1024))[tid] = r4;
    }
  } else if (bid < 6144) {
    int r = bid - 4096;
    float4 x = ((const float4*)(rel_enc + (size_t)r * 1024))[tid];
    ushort4 o;
    o.x = f2bf(x.x); o.y = f2bf(x.y); o.z = f2bf(x.z); o.w = f2bf(x.w);
    ((ushort4*)(reb + (size_t)r * 1024))[tid] = o;
  } else {
    __shared__ float tl[64][65];
    int idx = bid - 6144;
    int m = idx >> 8;
    int t = idx & 255;
    int k0 = (t >> 4) << 6, n0 = (t & 15) << 6;
    const float* srcw = wp.p[m];
    int kr = tid >> 4, nc = (tid & 15) << 2;
#pragma unroll
    for (int i = 0; i < 4; ++i) {
      int krow = i * 16 + kr;
      float4 v = *(const float4*)(srcw + (size_t)(k0 + krow) * 1024 + n0 + nc);
      tl[nc + 0][krow] = v.x;
      tl[nc + 1][krow] = v.y;
      tl[nc + 2][krow] = v.z;
      tl[nc + 3][krow] = v.w;
    }
    __syncthreads();
    int n = tid >> 2, kc0 = (tid & 3) << 4;
    unsigned short* dst = wT + ((size_t)m << 20) + (size_t)(n0 + n) * 1024 + k0 + kc0;
#pragma unroll
    for (int q = 0; q < 4; ++q) {
      ushort4 o;
      o.x = f2bf(tl[n][kc0 + q * 4 + 0]);
      o.y = f2bf(tl[n][kc0 + q * 4 + 1]);
      o.z = f2bf(tl[n][kc0 + q * 4 + 2]);
      o.w = f2bf(tl[n][kc0 + q * 4 + 3]);
      *(ushort4*)(dst + q * 4) = o;
    }
  }
}

// ---------------------------------------------------------------------------
// k_ln: LayerNorm rows of fp32 (2048 x 1024) -> bf16
// ---------------------------------------------------------------------------
__global__ __launch_bounds__(256) void k_ln(
    const float* __restrict__ xin, const float* __restrict__ g1n,
    const float* __restrict__ b1n, unsigned short* __restrict__ outb) {
  __shared__ float red[8];
  int bid = blockIdx.x, tid = threadIdx.x;
  const float* src = xin + (size_t)bid * 1024;
  float4 x = ((const float4*)src)[tid];
  float s = x.x + x.y + x.z + x.w;
  float ss = x.x * x.x + x.y * x.y + x.z * x.z + x.w * x.w;
#pragma unroll
  for (int m = 32; m > 0; m >>= 1) {
    s += __shfl_down(s, m, 64);
    ss += __shfl_down(ss, m, 64);
  }
  int w = tid >> 6;
  if ((tid & 63) == 0) { red[w] = s; red[4 + w] = ss; }
  __syncthreads();
  s = red[0] + red[1] + red[2] + red[3];
  ss = red[4] + red[5] + red[6] + red[7];
  float mu = s * (1.f / 1024.f);
  float inv = rsqrtf(ss * (1.f / 1024.f) - mu * mu + 1e-5f);
  float4 g = ((const float4*)g1n)[tid];
  float4 bb = ((const float4*)b1n)[tid];
  ushort4 o;
  o.x = f2bf((x.x - mu) * inv * g.x + bb.x);
  o.y = f2bf((x.y - mu) * inv * g.y + bb.y);
  o.z = f2bf((x.z - mu) * inv * g.z + bb.z);
  o.w = f2bf((x.w - mu) * inv * g.w + bb.w);
  ((ushort4*)(outb + (size_t)bid * 1024))[tid] = o;
}

// ---------------------------------------------------------------------------
// GEMM: C[M,Nt] = A[M,1024] @ Wt[Nt,1024]^T, tile TM x 128, BK=64, 4 waves
// split the 128-col dim.  Double-buffered LDS (1 barrier/iter), global loads
// for kt+1 in flight under kt's MFMAs.
// ---------------------------------------------------------------------------
__device__ __forceinline__ int lds_u128(int r, int g) {
  return g * 128 + (r & ~7) + ((r ^ g) & 7);
}
template <int TM>
__device__ __forceinline__ int lds_uT(int r, int g) {
  return g * TM + (r & ~7) + ((r ^ g) & 7);
}

enum { EP_KV = 0, EP_QUV, EP_BF16, EP_GELU_F32, EP_GATE1,
       EP_GELU_B_BF16, EP_GELU_B_F32, EP_GATE2 };

template <int EP, int TM>
__global__ __launch_bounds__(256, 2) void k_gemm(
    const unsigned short* __restrict__ A, const unsigned short* __restrict__ Bw,
    int arow_add, int arow_mul,
    const float* __restrict__ bias, const float* __restrict__ auxA,
    const float* __restrict__ auxB, void* __restrict__ out0,
    void* __restrict__ out1) {
  constexpr int MI = TM / 16;
  constexpr int AU = TM / 32;
  __shared__ __align__(16) unsigned short As[2][TM * 64];
  __shared__ __align__(16) unsigned short Bs[2][128 * 64];
  int tid = threadIdx.x;
  int lane = tid & 63, wave = tid >> 6;
  int quad = lane >> 4, col = lane & 15;
  int bm = blockIdx.y, bn = blockIdx.x;
  f32x4 acc[MI][2] = {};
  int str = tid >> 3, stg = tid & 7;
  const unsigned short* aptr[AU];
  int au[AU];
  const unsigned short* bptr[4];
  int bu[4];
#pragma unroll
  for (int i = 0; i < AU; ++i) {
    int r = str + 32 * i;
    int gr = bm * TM + r;
    int ar = gr + arow_add + (gr >> 10) * arow_mul;
    aptr[i] = A + (size_t)ar * 1024 + stg * 8;
    au[i] = lds_uT<TM>(r, stg);
  }
#pragma unroll
  for (int i = 0; i < 4; ++i) {
    int r = str + 32 * i;
    bptr[i] = Bw + (size_t)(bn * 128 + r) * 1024 + stg * 8;
    bu[i] = lds_u128(r, stg);
  }
  uint4 av[AU], bv[4];
#pragma unroll
  for (int i = 0; i < AU; ++i) av[i] = *(const uint4*)(aptr[i]);
#pragma unroll
  for (int i = 0; i < 4; ++i) bv[i] = *(const uint4*)(bptr[i]);
#pragma unroll
  for (int i = 0; i < AU; ++i) ((uint4*)As[0])[au[i]] = av[i];
#pragma unroll
  for (int i = 0; i < 4; ++i) ((uint4*)Bs[0])[bu[i]] = bv[i];
  for (int kt = 0; kt < 16; ++kt) {
    __syncthreads();
    if (kt < 15) {
      int k0 = (kt + 1) * 64;
#pragma unroll
      for (int i = 0; i < AU; ++i) av[i] = *(const uint4*)(aptr[i] + k0);
#pragma unroll
      for (int i = 0; i < 4; ++i) bv[i] = *(const uint4*)(bptr[i] + k0);
    }
    int cur = kt & 1;
#pragma unroll
    for (int ks = 0; ks < 2; ++ks) {
      bf16x8 af[MI], bfr[2];
#pragma unroll
      for (int mi = 0; mi < MI; ++mi)
        af[mi] = ((const bf16x8*)As[cur])[lds_uT<TM>(mi * 16 + col, ks * 4 + quad)];
#pragma unroll
      for (int ni = 0; ni < 2; ++ni)
        bfr[ni] = ((const bf16x8*)Bs[cur])[lds_u128(wave * 32 + ni * 16 + col, ks * 4 + quad)];
#pragma unroll
      for (int mi = 0; mi < MI; ++mi)
#pragma unroll
        for (int ni = 0; ni < 2; ++ni)
          acc[mi][ni] = MFMA16(af[mi], bfr[ni], acc[mi][ni]);
    }
    if (kt < 15) {
      int nxt = cur ^ 1;
#pragma unroll
      for (int i = 0; i < AU; ++i) ((uint4*)As[nxt])[au[i]] = av[i];
#pragma unroll
      for (int i = 0; i < 4; ++i) ((uint4*)Bs[nxt])[bu[i]] = bv[i];
    }
  }
#pragma unroll
  for (int mi = 0; mi < MI; ++mi)
#pragma unroll
    for (int ni = 0; ni < 2; ++ni)
#pragma unroll
      for (int r = 0; r < 4; ++r) {
        int grow = bm * TM + mi * 16 + quad * 4 + r;
        int gcol = bn * 128 + wave * 32 + ni * 16 + col;
        float v = acc[mi][ni][r];
        size_t idx = (size_t)grow * 1024 + gcol;
        if constexpr (EP == EP_KV) {
          if (gcol < 1024) {
            ((unsigned short*)out0)[(size_t)grow * 1024 + gcol] = f2bf(v);
          } else {
            ((unsigned short*)out1)[(size_t)grow * 1024 + gcol - 1024] = f2bf(v);
          }
        } else if constexpr (EP == EP_QUV) {
          ((unsigned short*)out0)[idx] = f2bf(v + auxA[gcol]);
          ((unsigned short*)out1)[idx] = f2bf(v + auxB[gcol]);
        } else if constexpr (EP == EP_BF16) {
          ((unsigned short*)out0)[idx] = f2bf(v);
        } else if constexpr (EP == EP_GELU_F32) {
          ((float*)out0)[idx] = gelu_f(v);
        } else if constexpr (EP == EP_GATE1) {
          float a = v + bias[gcol];
          float sg = 1.f / (1.f + __expf(-a));
          float g1 = auxA[idx] + sg * auxB[idx];
          ((float*)out0)[idx] = g1;
          ((unsigned short*)out1)[idx] = f2bf(g1);
        } else if constexpr (EP == EP_GELU_B_BF16) {
          ((unsigned short*)out0)[idx] = f2bf(gelu_f(v + bias[gcol]));
        } else if constexpr (EP == EP_GELU_B_F32) {
          ((float*)out0)[idx] = gelu_f(v + bias[gcol]);
        } else {  // EP_GATE2
          float a = v + bias[gcol];
          float sg = 1.f / (1.f + __expf(-a));
          ((float*)out0)[idx] = auxA[idx] + sg * auxB[idx];
        }
      }
}

// ---------------------------------------------------------------------------
// k_tr: v (b,f,h,d) bf16 -> vT (b,h,d,f) bf16.  grid (32 bh, 32 ftile).
// ---------------------------------------------------------------------------
__global__ __launch_bounds__(256) void k_tr(
    const unsigned short* __restrict__ v, unsigned short* __restrict__ vT) {
  __shared__ unsigned short tl[64][72];
  int bh = blockIdx.x, ft = blockIdx.y;
  int b = bh >> 4, h = bh & 15;
  int f0 = ft * 64;
  int tid = threadIdx.x;
  int fr = tid >> 2, c0 = (tid & 3) * 16;
  *(uint4*)&tl[fr][c0] =
      *(const uint4*)(v + ((size_t)(b * 2048 + f0 + fr)) * 1024 + h * 64 + c0);
  __syncthreads();
  int dr = tid >> 2, fc = (tid & 3) * 16;
  unsigned short* dst =
      vT + (((size_t)(b * 16 + h) * 64 + dr)) * 2048 + f0 + fc;
#pragma unroll
  for (int q = 0; q < 4; ++q) {
    ushort4 o;
    o.x = tl[fc + q * 4 + 0][dr];
    o.y = tl[fc + q * 4 + 1][dr];
    o.z = tl[fc + q * 4 + 2][dr];
    o.w = tl[fc + q * 4 + 3][dr];
    *(ushort4*)(dst + q * 4) = o;
  }
}

// ---------------------------------------------------------------------------
// Fused rel-pos attention, pass 1 only.  grid (32 = B*H, 64 = S/16);
// block 256 = 4 waves; block owns 16 query rows, wave w owns cols
// [w*512, w*512+512).  Writes UNNORMALIZED p (fp32) into the attn output
// region, accumulates rowsum + P@V, cross-wave reduces, writes ao (bf16),
// rinvb (fp32 per row) and per-(b,h) max of p*rinv -> atomicMax(amax).
// All global loads per 32-col chunk are hoisted for ILP.
// ---------------------------------------------------------------------------
__global__ __launch_bounds__(256) void k_att(
    const unsigned short* __restrict__ qu, const unsigned short* __restrict__ qv,
    const unsigned short* __restrict__ kk, const unsigned short* __restrict__ vT,
    const unsigned short* __restrict__ Qr,
    float* __restrict__ attn, unsigned short* __restrict__ ao,
    float* __restrict__ rinvb, float* __restrict__ amax) {
  __shared__ __align__(16) unsigned short Pl[4][512];
  __shared__ __align__(16) float Ol[2][1024];
  __shared__ float Sl[4][16];
  __shared__ float Rinv[16];
  int tid = threadIdx.x, lane = tid & 63, wave = tid >> 6;
  int quad = lane >> 4, col = lane & 15;
  int bh = blockIdx.x, rt = blockIdx.y;
  int b = bh >> 4, h = bh & 15;
  int ri = rt * 16;

  bf16x8 quf[2], qvf[2];
  {
    const unsigned short* p0 = qu + ((size_t)(b * 1024 + ri + col)) * 1024 + h * 64 + quad * 8;
    quf[0] = *(const bf16x8*)p0;
    quf[1] = *(const bf16x8*)(p0 + 32);
    const unsigned short* p1 = qv + ((size_t)(b * 1024 + ri + col)) * 1024 + h * 64 + quad * 8;
    qvf[0] = *(const bf16x8*)p1;
    qvf[1] = *(const bf16x8*)(p1 + 32);
  }

  const unsigned short* qrbase = Qr + h * 64 + quad * 8;
  auto r_load = [&](int cbase, bf16x8& b0, bf16x8& b1) {
    int cr = cbase + col;
    cr = cr < 0 ? 0 : (cr > 2047 ? 2047 : cr);
    const unsigned short* p = qrbase + (size_t)cr * 1024;
    b0 = *(const bf16x8*)p;
    b1 = *(const bf16x8*)(p + 32);
  };
  auto r_mm = [&](bf16x8 b0, bf16x8 b1) -> f32x4 {
    f32x4 z = {0.f, 0.f, 0.f, 0.f};
    z = MFMA16(qvf[0], b0, z);
    z = MFMA16(qvf[1], b1, z);
    return z;
  };

  const unsigned short* kbase = kk + ((size_t)(b * 2048)) * 1024 + h * 64 + quad * 8;
  const unsigned short* vbase = vT + ((size_t)((b * 16 + h) * 64)) * 2048;
  float* arow0 = attn + ((size_t)bh * 1024 + ri + quad * 4) * 2048 + col;

  f32x4 o4[4] = {};
  f32x4 srow = {0.f, 0.f, 0.f, 0.f};
  f32x4 pm = {0.f, 0.f, 0.f, 0.f};
  int jmax = ri + 15 + 1024;
  int jlo = wave * 512;

  if (jlo <= jmax) {
    int hi = jmax < jlo + 511 ? jmax : jlo + 511;
    int nch = ((hi - jlo) >> 5) + 1;
    int cw = 1008 - ri + jlo;
    f32x4 Rcur;
    {
      bf16x8 rb0, rb1;
      r_load(cw, rb0, rb1);
      Rcur = r_mm(rb0, rb1);
    }
    for (int ch = 0; ch < nch; ++ch) {
      int j0 = jlo + ch * 32;
      // ---- hoisted global loads (12 in flight) ----
      bf16x8 ra0, ra1, rc0, rc1;
      r_load(cw + 16, ra0, ra1);
      r_load(cw + 32, rc0, rc1);
      const unsigned short* kp0 = kbase + (size_t)(j0 + col) * 1024;
      const unsigned short* kp1 = kbase + (size_t)(j0 + 16 + col) * 1024;
      bf16x8 k00 = *(const bf16x8*)kp0;
      bf16x8 k01 = *(const bf16x8*)(kp0 + 32);
      bf16x8 k10 = *(const bf16x8*)kp1;
      bf16x8 k11 = *(const bf16x8*)(kp1 + 32);
      int fb = j0 + quad * 8;
      bf16x8 vf[4];
#pragma unroll
      for (int ni = 0; ni < 4; ++ni)
        vf[ni] = *(const bf16x8*)(vbase + (size_t)(ni * 16 + col) * 2048 + fb);
      // ---- compute ----
      f32x4 Rn1 = r_mm(ra0, ra1);
      f32x4 Rn2 = r_mm(rc0, rc1);
      f32x4 ac0 = {0.f, 0.f, 0.f, 0.f};
      ac0 = MFMA16(quf[0], k00, ac0);
      ac0 = MFMA16(quf[1], k01, ac0);
      f32x4 ac1 = {0.f, 0.f, 0.f, 0.f};
      ac1 = MFMA16(quf[0], k10, ac1);
      ac1 = MFMA16(quf[1], k11, ac1);
#pragma unroll
      for (int r = 0; r < 4; ++r) {
        int w = 15 + col - quad * 4 - r;
        int src = quad * 16 + (w & 15);
        float bd0 = __shfl(Rcur[r], src, 64);
        float bd1 = __shfl(Rn1[r], src, 64);
        float bd = (w < 16) ? bd0 : bd1;
        float sc = (ac0[r] + bd) * 0.03125f;
        int masked = (j0 + col) > (ri + quad * 4 + r + 1024);
        float p = masked ? 0.f : __expf(sc);
        srow[r] += p;
        pm[r] = fmaxf(pm[r], p);
        arow0[(size_t)r * 2048 + j0] = p;
        Pl[wave][(quad * 4 + r) * 32 + col] = f2bf(p);
      }
#pragma unroll
      for (int r = 0; r < 4; ++r) {
        int w = 15 + col - quad * 4 - r;
        int src = quad * 16 + (w & 15);
        float bd0 = __shfl(Rn1[r], src, 64);
        float bd1 = __shfl(Rn2[r], src, 64);
        float bd = (w < 16) ? bd0 : bd1;
        float sc = (ac1[r] + bd) * 0.03125f;
        int masked = (j0 + 16 + col) > (ri + quad * 4 + r + 1024);
        float p = masked ? 0.f : __expf(sc);
        srow[r] += p;
        pm[r] = fmaxf(pm[r], p);
        arow0[(size_t)r * 2048 + j0 + 16] = p;
        Pl[wave][(quad * 4 + r) * 32 + 16 + col] = f2bf(p);
      }
      asm volatile("s_waitcnt lgkmcnt(0)" ::: "memory");
      bf16x8 pf = *(const bf16x8*)&Pl[wave][col * 32 + quad * 8];
#pragma unroll
      for (int ni = 0; ni < 4; ++ni) o4[ni] = MFMA16(pf, vf[ni], o4[ni]);
      Rcur = Rn2;
      cw += 32;
    }
  }
  // stripe row-sums / row-max (reduce across the 16 col lanes of each quad)
#pragma unroll
  for (int r = 0; r < 4; ++r) {
    float v = srow[r], m = pm[r];
    v += __shfl_xor(v, 1, 64);  m = fmaxf(m, __shfl_xor(m, 1, 64));
    v += __shfl_xor(v, 2, 64);  m = fmaxf(m, __shfl_xor(m, 2, 64));
    v += __shfl_xor(v, 4, 64);  m = fmaxf(m, __shfl_xor(m, 4, 64));
    v += __shfl_xor(v, 8, 64);  m = fmaxf(m, __shfl_xor(m, 8, 64));
    srow[r] = v; pm[r] = m;
  }
  if (col == 0) {
#pragma unroll
    for (int r = 0; r < 4; ++r) Sl[wave][quad * 4 + r] = srow[r];
  }
  if (wave >= 2) {
#pragma unroll
    for (int ni = 0; ni < 4; ++ni)
#pragma unroll
      for (int r = 0; r < 4; ++r)
        Ol[wave - 2][(quad * 4 + r) * 64 + ni * 16 + col] = o4[ni][r];
  }
  __syncthreads();
  if (tid < 16) {
    float rv = 1.f / (Sl[0][tid] + Sl[1][tid] + Sl[2][tid] + Sl[3][tid]);
    Rinv[tid] = rv;
    rinvb[(size_t)bh * 1024 + ri + tid] = rv;
  }
  if (wave < 2) {
#pragma unroll
    for (int ni = 0; ni < 4; ++ni)
#pragma unroll
      for (int r = 0; r < 4; ++r) {
        int ix = (quad * 4 + r) * 64 + ni * 16 + col;
        o4[ni][r] += Ol[wave][ix];
        if (wave == 1) Ol[1][ix] = o4[ni][r];
      }
  }
  __syncthreads();
  if (wave == 0) {
#pragma unroll
    for (int ni = 0; ni < 4; ++ni)
#pragma unroll
      for (int r = 0; r < 4; ++r) {
        int ix = (quad * 4 + r) * 64 + ni * 16 + col;
        o4[ni][r] += Ol[1][ix];
        Ol[0][ix] = o4[ni][r];
      }
  }
  __syncthreads();
  {
    int row = tid >> 4, d0 = (tid & 15) << 2;
    float4 ov = *(const float4*)&Ol[0][row * 64 + d0];
    float rv = Rinv[row];
    ushort4 o;
    o.x = f2bf(ov.x * rv); o.y = f2bf(ov.y * rv);
    o.z = f2bf(ov.z * rv); o.w = f2bf(ov.w * rv);
    *(ushort4*)(ao + ((size_t)(b * 1024 + ri + row)) * 1024 + h * 64 + d0) = o;
  }
  // per-(b,h) max of normalized p
  float pmax = 0.f;
#pragma unroll
  for (int r = 0; r < 4; ++r) pmax = fmaxf(pmax, pm[r] * Rinv[quad * 4 + r]);
  pmax = fmaxf(pmax, __shfl_xor(pmax, 16, 64));
  pmax = fmaxf(pmax, __shfl_xor(pmax, 32, 64));
  if (lane == 0) atomicMax((int*)(amax + bh), __float_as_int(pmax));
}

// ---------------------------------------------------------------------------
// k_norm: in-place attn normalize.  grid 32768 blocks (one per row), 256 thr.
// val = (j <= s+1024) ? p * rinv[row] : 0
// ---------------------------------------------------------------------------
__global__ __launch_bounds__(256) void k_norm(
    float* __restrict__ attn, const float* __restrict__ rinvb) {
  int gr = blockIdx.x;
  int s = gr & 1023;
  float rv = rinvb[gr];
  int j0 = threadIdx.x * 8;
  int lim = s + 1024;
  float* row = attn + (size_t)gr * 2048 + j0;
  float4 a = {0.f, 0.f, 0.f, 0.f}, b4 = {0.f, 0.f, 0.f, 0.f};
  if (j0 <= lim) {
    a = ((const float4*)row)[0];
    b4 = ((const float4*)row)[1];
  }
  float4 oa, ob;
  oa.x = (j0 + 0 <= lim) ? a.x * rv : 0.f;
  oa.y = (j0 + 1 <= lim) ? a.y * rv : 0.f;
  oa.z = (j0 + 2 <= lim) ? a.z * rv : 0.f;
  oa.w = (j0 + 3 <= lim) ? a.w * rv : 0.f;
  ob.x = (j0 + 4 <= lim) ? b4.x * rv : 0.f;
  ob.y = (j0 + 5 <= lim) ? b4.y * rv : 0.f;
  ob.z = (j0 + 6 <= lim) ? b4.z * rv : 0.f;
  ob.w = (j0 + 7 <= lim) ? b4.w * rv : 0.f;
  ((float4*)row)[0] = oa;
  ((float4*)row)[1] = ob;
}

// ---------------------------------------------------------------------------
__global__ void k_loss(const float* __restrict__ amax, float* __restrict__ out) {
  int l = threadIdx.x;
  float v = (l < 32) ? amax[l] : 0.f;
  v += __shfl_xor(v, 1, 64);
  v += __shfl_xor(v, 2, 64);
  v += __shfl_xor(v, 4, 64);
  v += __shfl_xor(v, 8, 64);
  v += __shfl_xor(v, 16, 64);
  v += __shfl_xor(v, 32, 64);
  if (l == 0) out[0] = v * (1.f / 32.f);
}

// ---------------------------------------------------------------------------
extern "C" void kernel_launch(void* const* d_in, const int* in_sizes, int n_in,
                              void* d_out, int out_size, void* d_ws, size_t ws_size,
                              hipStream_t stream) {
  (void)in_sizes; (void)n_in; (void)out_size; (void)ws_size;
  const float* inputs = (const float*)d_in[0];
  const float* mem    = (const float*)d_in[1];
  const float* rel    = (const float*)d_in[2];
  const float* ln1g   = (const float*)d_in[4];
  const float* ln1b   = (const float*)d_in[5];
  const float* wq     = (const float*)d_in[6];
  const float* wke    = (const float*)d_in[7];
  const float* wkr    = (const float*)d_in[8];
  const float* wv     = (const float*)d_in[9];
  const float* wf     = (const float*)d_in[10];
  const float* up     = (const float*)d_in[11];
  const float* vp     = (const float*)d_in[12];
  const float* ln2g   = (const float*)d_in[13];
  const float* ln2b   = (const float*)d_in[14];
  const float* w1     = (const float*)d_in[15];
  const float* b1     = (const float*)d_in[16];
  const float* w2     = (const float*)d_in[17];
  const float* b2     = (const float*)d_in[18];
  const float* wg1    = (const float*)d_in[19];
  const float* bg1    = (const float*)d_in[20];
  const float* wg2    = (const float*)d_in[21];
  const float* bg2    = (const float*)d_in[22];

  char* ws = (char*)d_ws;
  unsigned short* wT  = (unsigned short*)(ws);              // 18 MB (9 x 1Mel)
  unsigned short* xt  = (unsigned short*)(ws + 18874368);   // 8 MB
  unsigned short* inb = (unsigned short*)(ws + 27262976);   // 4 MB
  unsigned short* reb = (unsigned short*)(ws + 31457280);   // 4 MB
  unsigned short* kb  = (unsigned short*)(ws + 35651584);   // 8 MB
  unsigned short* vTb = (unsigned short*)(ws + 44040192);   // 8 MB
  unsigned short* qub = (unsigned short*)(ws + 52428800);   // 4 MB
  unsigned short* qvb = (unsigned short*)(ws + 56623104);   // 4 MB
  unsigned short* Qrb = (unsigned short*)(ws + 60817408);   // 4 MB
  float* amax         = (float*)(ws + 65011712);            // 128 B
  float* rinvb        = (float*)(ws + 65012736);            // 128 KB
  // aliases onto dead buffers:
  unsigned short* vb = qub;          // v row-major, dead after k_tr (8 MB)
  float* rmha = (float*)xt;
  unsigned short* aob = reb;
  float* g1f = (float*)kb;
  float* h2f = (float*)vTb;
  unsigned short* g1b = qub;
  unsigned short* h0b = qvb;
  unsigned short* h1b = Qrb;

  float* outp  = (float*)d_out;
  float* attnp = outp + 2097152;
  float* lossp = outp + 69206016;

  W9 wp;
  wp.p[0] = wq;  wp.p[1] = wke; wp.p[2] = wv;  wp.p[3] = wkr; wp.p[4] = wf;
  wp.p[5] = w1;  wp.p[6] = w2;  wp.p[7] = wg1; wp.p[8] = wg2;

  k_init<<<8448, 256, 0, stream>>>(inputs, mem, rel, ln1g, ln1b, wp,
                                   xt, inb, reb, wT, amax);
  // k|v fused: (B*F,1024) @ [wke|wv]^T  (N=2048); both halves row-major
  k_gemm<EP_KV, 64><<<dim3(16, 64), 256, 0, stream>>>(
      xt, wT + (1u << 20), 0, 0, nullptr, nullptr, nullptr, kb, vb);
  // vT (b,h,d,f) from v (b,f,h,d)
  k_tr<<<dim3(32, 32), 256, 0, stream>>>(vb, vTb);
  // q -> qu = q+u_param, qv = q+v_param  (A rows = x_tilde[:, -S:]) — clobbers vb
  k_gemm<EP_QUV, 32><<<dim3(8, 64), 256, 0, stream>>>(
      xt, wT, 1024, 1024, nullptr, up, vp, qub, qvb);
  // Qr = rel_enc @ wkr
  k_gemm<EP_BF16, 32><<<dim3(8, 64), 256, 0, stream>>>(
      reb, wT + 3u * (1u << 20), 0, 0, nullptr, nullptr, nullptr, Qrb, nullptr);
  // attention pass 1: unnormalized p into attn region, ao, rinvb, amax
  k_att<<<dim3(32, 64), 256, 0, stream>>>(qub, qvb, kb, vTb, Qrb,
                                          attnp, aob, rinvb, amax);
  // normalize attn in place
  k_norm<<<32768, 256, 0, stream>>>(attnp, rinvb);
  // rmha = gelu(ao @ wf)
  k_gemm<EP_GELU_F32, 32><<<dim3(8, 64), 256, 0, stream>>>(
      aob, wT + 4u * (1u << 20), 0, 0, nullptr, nullptr, nullptr, rmha, nullptr);
  // g1 = inputs + sigmoid(inputs@wg1 + bg1) * rmha
  k_gemm<EP_GATE1, 32><<<dim3(8, 64), 256, 0, stream>>>(
      inb, wT + 7u * (1u << 20), 0, 0, bg1, inputs, rmha, g1f, g1b);
  // h0 = LN2(g1)
  k_ln<<<2048, 256, 0, stream>>>(g1f, ln2g, ln2b, h0b);
  // h1 = gelu(h0@w1 + b1)
  k_gemm<EP_GELU_B_BF16, 32><<<dim3(8, 64), 256, 0, stream>>>(
      h0b, wT + 5u * (1u << 20), 0, 0, b1, nullptr, nullptr, h1b, nullptr);
  // h2 = gelu(h1@w2 + b2)
  k_gemm<EP_GELU_B_F32, 32><<<dim3(8, 64), 256, 0, stream>>>(
      h1b, wT + 6u * (1u << 20), 0, 0, b2, nullptr, nullptr, h2f, nullptr);
  // out = g1 + sigmoid(g1@wg2 + bg2) * h2
  k_gemm<EP_GATE2, 32><<<dim3(8, 64), 256, 0, stream>>>(
      g1b, wT + 8u * (1u << 20), 0, 0, bg2, g1f, h2f, outp, nullptr);
  k_loss<<<1, 64, 0, stream>>>(amax, lossp);
}